// Round 1
// 723.930 us; speedup vs baseline: 1.0859x; 1.0859x over previous
//
#include <hip/hip_runtime.h>
#include <hip/hip_fp16.h>
#include <math.h>

// Problem constants
#define S 2048
#define D 64
#define BH 32          // B*H = 2*16
#define TILE 64
#define NT (S / TILE)  // 32
#define SP1 (S + 1)    // 2049

typedef _Float16 f16;
typedef f16 f16x8 __attribute__((ext_vector_type(8)));
typedef f16 f16x4 __attribute__((ext_vector_type(4)));
typedef float f32x4 __attribute__((ext_vector_type(4)));

#define LDS_PITCH 72   // halfs per row: 64 + 8 pad (16B-aligned, 2-way bank alias = free)

// ---------------------------------------------------------------------------
// Phase 1: rinv[bh*S + j] = 1/||k_j||   (one wave per row, lane d holds k[j][d])
// ---------------------------------------------------------------------------
__global__ __launch_bounds__(256) void knorm_kernel(const float* __restrict__ k,
                                                    float* __restrict__ rinv) {
    int row  = (blockIdx.x * 256 + threadIdx.x) >> 6;
    int lane = threadIdx.x & 63;
    float v = k[(size_t)row * D + lane];
    float s = v * v;
    #pragma unroll
    for (int off = 32; off; off >>= 1) s += __shfl_xor(s, off);
    if (lane == 0) rinv[row] = 1.0f / sqrtf(s);
}

// ---------------------------------------------------------------------------
// Fused: one block per (row-tile it, bh). Pass 1 computes rowsums (-> inv_l in
// LDS, no global round-trip). Pass 2 sweeps the whole 2049-col row strip
// left->right so every output cache line is produced by ONE block with
// temporal locality (full-line L2 evictions despite the 8196 B row stride).
// MFMA 16x16x32 f16. C/D: col=lane&15, row=(lane>>4)*4+reg.
// ---------------------------------------------------------------------------
__global__ __launch_bounds__(256) void fused_kernel(
    const float* __restrict__ q, const float* __restrict__ k,
    const float* __restrict__ sinks, const float* __restrict__ rinv,
    float* __restrict__ out)
{
    __shared__ __align__(16) f16 qs[TILE * LDS_PITCH];
    __shared__ __align__(16) f16 ks[TILE * LDS_PITCH];
    __shared__ float ils[TILE];

    const int it = NT - 1 - blockIdx.x;   // longest (most causal tiles) first
    const int bh = blockIdx.y;
    const int i0 = it * TILE;
    const int tid  = threadIdx.x;
    const int lane = tid & 63;
    const int w    = tid >> 6;
    const int m    = lane & 15;
    const int quad = lane >> 4;

    const float* qbase = q + (size_t)bh * S * D;
    const float* kbase = k + (size_t)bh * S * D;
    const float* rbase = rinv + (size_t)bh * S;
    float* obase = out + (size_t)bh * S * SP1;

    // stage q tile (fp32 -> f16)
    {
        int r  = tid >> 4;
        int c4 = (tid & 15) * 4;
        #pragma unroll
        for (int rb = 0; rb < 4; rb++) {
            int row = rb * 16 + r;
            float4 v = *(const float4*)(qbase + (size_t)(i0 + row) * D + c4);
            f16x4 hv; hv[0] = (f16)v.x; hv[1] = (f16)v.y; hv[2] = (f16)v.z; hv[3] = (f16)v.w;
            *(f16x4*)&qs[row * LDS_PITCH + c4] = hv;
        }
    }
    __syncthreads();

    // A fragments (q rows w*16..w*16+15), both K=32 halves of D=64
    f16x8 a0 = *(const f16x8*)&qs[(w * 16 + m) * LDS_PITCH + 0  + quad * 8];
    f16x8 a1 = *(const f16x8*)&qs[(w * 16 + m) * LDS_PITCH + 32 + quad * 8];

    const int ib = i0 + w * 16 + quad * 4;   // first of 4 rows this lane owns

    // ---------------- pass 1: row denominators ----------------
    float rowsum[4] = {0.f, 0.f, 0.f, 0.f};
    for (int jt = 0; jt <= it; jt++) {
        const int j0 = jt * TILE;
        __syncthreads();   // prior iter done reading ks
        {
            int r  = tid >> 4;
            int c4 = (tid & 15) * 4;
            #pragma unroll
            for (int rb = 0; rb < 4; rb++) {
                int row = rb * 16 + r;
                float4 v = *(const float4*)(kbase + (size_t)(j0 + row) * D + c4);
                f16x4 hv; hv[0] = (f16)v.x; hv[1] = (f16)v.y; hv[2] = (f16)v.z; hv[3] = (f16)v.w;
                *(f16x4*)&ks[row * LDS_PITCH + c4] = hv;
            }
        }
        __syncthreads();

        const bool diag = (jt == it);
        #pragma unroll
        for (int st = 0; st < 4; st++) {
            f16x8 b0 = *(const f16x8*)&ks[(st * 16 + m) * LDS_PITCH + 0  + quad * 8];
            f16x8 b1 = *(const f16x8*)&ks[(st * 16 + m) * LDS_PITCH + 32 + quad * 8];
            f32x4 acc = {0.f, 0.f, 0.f, 0.f};
            acc = __builtin_amdgcn_mfma_f32_16x16x32_f16(a0, b0, acc, 0, 0, 0);
            acc = __builtin_amdgcn_mfma_f32_16x16x32_f16(a1, b1, acc, 0, 0, 0);
            const int j = j0 + st * 16 + m;
            const float rj = rbase[j];
            #pragma unroll
            for (int r = 0; r < 4; r++) {
                float e = __expf(acc[r] * rj);
                if (diag && j > ib + r) e = 0.0f;   // upper-tri handled in closed form
                rowsum[r] += e;
            }
        }
    }

    // reduce across the 16 lanes of each quad (columns of the score tile)
    #pragma unroll
    for (int off = 1; off < 16; off <<= 1)
        #pragma unroll
        for (int r = 0; r < 4; r++) rowsum[r] += __shfl_xor(rowsum[r], off);

    if (m == 0) {
        #pragma unroll
        for (int r = 0; r < 4; r++) {
            int i = ib + r;
            float l = rowsum[r] + (float)(S - 1 - i) + __expf(sinks[bh * S + i]);
            ils[w * 16 + quad * 4 + r] = 1.0f / l;
        }
    }
    __syncthreads();

    // sink column (col S), one value per row, from LDS
    if (tid < TILE) {
        int i = i0 + tid;
        obase[(size_t)i * SP1 + S] = __expf(sinks[bh * S + i]) * ils[tid];
    }

    float il[4];
    #pragma unroll
    for (int r = 0; r < 4; r++) il[r] = ils[w * 16 + quad * 4 + r];

    // ---------------- pass 2: output sweep, jt = 0..NT-1 ----------------
    for (int jt = 0; jt < NT; jt++) {
        const int j0 = jt * TILE;
        if (jt <= it) {
            __syncthreads();   // everyone done reading ks (or the ils barrier)
            {
                int r  = tid >> 4;
                int c4 = (tid & 15) * 4;
                #pragma unroll
                for (int rb = 0; rb < 4; rb++) {
                    int row = rb * 16 + r;
                    float4 v = *(const float4*)(kbase + (size_t)(j0 + row) * D + c4);
                    f16x4 hv; hv[0] = (f16)v.x; hv[1] = (f16)v.y; hv[2] = (f16)v.z; hv[3] = (f16)v.w;
                    *(f16x4*)&ks[row * LDS_PITCH + c4] = hv;
                }
            }
            __syncthreads();

            const bool diag = (jt == it);
            #pragma unroll
            for (int st = 0; st < 4; st++) {
                f16x8 b0 = *(const f16x8*)&ks[(st * 16 + m) * LDS_PITCH + 0  + quad * 8];
                f16x8 b1 = *(const f16x8*)&ks[(st * 16 + m) * LDS_PITCH + 32 + quad * 8];
                f32x4 acc = {0.f, 0.f, 0.f, 0.f};
                acc = __builtin_amdgcn_mfma_f32_16x16x32_f16(a0, b0, acc, 0, 0, 0);
                acc = __builtin_amdgcn_mfma_f32_16x16x32_f16(a1, b1, acc, 0, 0, 0);
                const int j = j0 + st * 16 + m;
                const float rj = rbase[j];
                #pragma unroll
                for (int r = 0; r < 4; r++) {
                    float val = __expf(acc[r] * rj) * il[r];
                    if (diag && j > ib + r) val = il[r];   // exp(0)/l
                    obase[(size_t)(ib + r) * SP1 + j] = val;
                }
            }
        } else {
            // broadcast tiles: 256 B contiguous per wave per row, value uniform
            const int cb = lane;            // 0..63
            #pragma unroll
            for (int r = 0; r < 16; r++) {
                int row = w * 16 + r;
                obase[(size_t)(i0 + row) * SP1 + j0 + cb] = ils[row];
            }
        }
    }
}

// ---------------------------------------------------------------------------
extern "C" void kernel_launch(void* const* d_in, const int* in_sizes, int n_in,
                              void* d_out, int out_size, void* d_ws, size_t ws_size,
                              hipStream_t stream) {
    const float* q     = (const float*)d_in[0];
    const float* k     = (const float*)d_in[1];
    const float* sinks = (const float*)d_in[2];
    float* out = (float*)d_out;

    float* rinv = (float*)d_ws;   // BH*S floats

    knorm_kernel<<<dim3(BH * S / 4), 256, 0, stream>>>(k, rinv);
    fused_kernel<<<dim3(NT, BH), 256, 0, stream>>>(q, k, sinks, rinv, out);
}

// Round 2
// 697.630 us; speedup vs baseline: 1.1268x; 1.0377x over previous
//
#include <hip/hip_runtime.h>
#include <hip/hip_fp16.h>
#include <math.h>

// Problem constants
#define S 2048
#define D 64
#define BH 32          // B*H = 2*16
#define TILE 64
#define NT (S / TILE)  // 32
#define SP1 (S + 1)    // 2049

typedef _Float16 f16;
typedef f16 f16x8 __attribute__((ext_vector_type(8)));
typedef f16 f16x4 __attribute__((ext_vector_type(4)));
typedef float f32x4 __attribute__((ext_vector_type(4)));

// 16-byte store with only 4-byte alignment guarantee (row stride 8196 B).
// packed+aligned(4) lets LLVM emit global_store_dwordx4 with align 4.
struct __attribute__((packed, aligned(4))) f4u { float x, y, z, w; };

#define LDS_PITCH 72   // halfs per row: 64 + 8 pad (16B-aligned, 2-way bank alias = free)

// ---------------------------------------------------------------------------
// Phase 1: rinv[bh*S + j] = 1/||k_j||   (one wave per row, lane d holds k[j][d])
// ---------------------------------------------------------------------------
__global__ __launch_bounds__(256) void knorm_kernel(const float* __restrict__ k,
                                                    float* __restrict__ rinv) {
    int row  = (blockIdx.x * 256 + threadIdx.x) >> 6;
    int lane = threadIdx.x & 63;
    float v = k[(size_t)row * D + lane];
    float s = v * v;
    #pragma unroll
    for (int off = 32; off; off >>= 1) s += __shfl_xor(s, off);
    if (lane == 0) rinv[row] = 1.0f / sqrtf(s);
}

// ---------------------------------------------------------------------------
// Fused: one block per (row-tile it, bh).
// Pass 1: rowsums over causal tiles -> inv_l in LDS (no global round-trip).
// Pass 2: compute tiles jt = it..0 (backwards: tile `it` already resident),
//         then broadcast tiles with dwordx4 stores, then sink column.
// K tiles are double-buffered with register-staged prefetch: loads for tile
// n+1 are issued BEFORE computing tile n; ds_write after compute; ONE barrier
// per iteration. Hides the ~900cy load latency under MFMA+exp.
// MFMA 16x16x32 f16. C/D: col=lane&15, row=(lane>>4)*4+reg.
// ---------------------------------------------------------------------------
__global__ __launch_bounds__(256) void fused_kernel(
    const float* __restrict__ q, const float* __restrict__ k,
    const float* __restrict__ sinks, const float* __restrict__ rinv,
    float* __restrict__ out)
{
    __shared__ __align__(16) f16 qs[TILE * LDS_PITCH];
    __shared__ __align__(16) f16 ks[2][TILE * LDS_PITCH];
    __shared__ float ils[TILE];

    const int it = NT - 1 - blockIdx.x;   // longest (most causal tiles) first
    const int bh = blockIdx.y;
    const int i0 = it * TILE;
    const int tid  = threadIdx.x;
    const int lane = tid & 63;
    const int w    = tid >> 6;
    const int m    = lane & 15;
    const int quad = lane >> 4;
    const int sr   = tid >> 4;          // staging row within each 16-row group
    const int sc4  = (tid & 15) * 4;    // staging col (floats)

    const float* qbase = q + (size_t)bh * S * D;
    const float* kbase = k + (size_t)bh * S * D;
    const float* rbase = rinv + (size_t)bh * S;
    float* obase = out + (size_t)bh * S * SP1;

    float4 pre[4];   // in-flight K tile (register staged)

    auto loadk = [&](int jt) {
        const float* tb = kbase + (size_t)(jt * TILE) * D;
        #pragma unroll
        for (int rb = 0; rb < 4; rb++)
            pre[rb] = *(const float4*)(tb + (size_t)(rb * 16 + sr) * D + sc4);
    };
    auto writek = [&](int buf) {
        #pragma unroll
        for (int rb = 0; rb < 4; rb++) {
            float4 v = pre[rb];
            f16x4 hv; hv[0] = (f16)v.x; hv[1] = (f16)v.y; hv[2] = (f16)v.z; hv[3] = (f16)v.w;
            *(f16x4*)&ks[buf][(rb * 16 + sr) * LDS_PITCH + sc4] = hv;
        }
    };

    // prologue: K tile 0 + q tile staged together
    loadk(0);
    {
        #pragma unroll
        for (int rb = 0; rb < 4; rb++) {
            int row = rb * 16 + sr;
            float4 v = *(const float4*)(qbase + (size_t)(i0 + row) * D + sc4);
            f16x4 hv; hv[0] = (f16)v.x; hv[1] = (f16)v.y; hv[2] = (f16)v.z; hv[3] = (f16)v.w;
            *(f16x4*)&qs[row * LDS_PITCH + sc4] = hv;
        }
    }
    writek(0);
    __syncthreads();

    // A fragments (q rows w*16..w*16+15), both K=32 halves of D=64
    f16x8 a0 = *(const f16x8*)&qs[(w * 16 + m) * LDS_PITCH + 0  + quad * 8];
    f16x8 a1 = *(const f16x8*)&qs[(w * 16 + m) * LDS_PITCH + 32 + quad * 8];

    const int ib = i0 + w * 16 + quad * 4;   // first of 4 rows this lane owns

    // ---------------- pass 1: row denominators ----------------
    float rowsum[4] = {0.f, 0.f, 0.f, 0.f};
    for (int jt = 0; jt <= it; jt++) {
        if (jt < it) loadk(jt + 1);          // prefetch next tile -> regs
        const int buf = jt & 1;
        const bool diag = (jt == it);
        const int j0 = jt * TILE;
        #pragma unroll
        for (int st = 0; st < 4; st++) {
            f16x8 b0 = *(const f16x8*)&ks[buf][(st * 16 + m) * LDS_PITCH + 0  + quad * 8];
            f16x8 b1 = *(const f16x8*)&ks[buf][(st * 16 + m) * LDS_PITCH + 32 + quad * 8];
            f32x4 acc = {0.f, 0.f, 0.f, 0.f};
            acc = __builtin_amdgcn_mfma_f32_16x16x32_f16(a0, b0, acc, 0, 0, 0);
            acc = __builtin_amdgcn_mfma_f32_16x16x32_f16(a1, b1, acc, 0, 0, 0);
            const int j = j0 + st * 16 + m;
            const float rj = rbase[j];
            #pragma unroll
            for (int r = 0; r < 4; r++) {
                float e = __expf(acc[r] * rj);
                if (diag && j > ib + r) e = 0.0f;   // upper-tri handled in closed form
                rowsum[r] += e;
            }
        }
        if (jt < it) writek((jt + 1) & 1);   // other buffer: safe, last read 1 iter ago
        __syncthreads();
    }

    // reduce across the 16 lanes of each quad (columns of the score tile)
    #pragma unroll
    for (int off = 1; off < 16; off <<= 1)
        #pragma unroll
        for (int r = 0; r < 4; r++) rowsum[r] += __shfl_xor(rowsum[r], off);

    if (m == 0) {
        #pragma unroll
        for (int r = 0; r < 4; r++) {
            int i = ib + r;
            float l = rowsum[r] + (float)(S - 1 - i) + __expf(sinks[bh * S + i]);
            ils[w * 16 + quad * 4 + r] = 1.0f / l;
        }
    }
    __syncthreads();

    // sink column (col S), one value per row, from LDS
    if (tid < TILE) {
        int i = i0 + tid;
        obase[(size_t)i * SP1 + S] = __expf(sinks[bh * S + i]) * ils[tid];
    }

    float il[4];
    #pragma unroll
    for (int r = 0; r < 4; r++) il[r] = ils[w * 16 + quad * 4 + r];

    // ---------------- pass 2a: compute tiles, jt = it..0 (tile it resident) --
    for (int jt = it; jt >= 0; jt--) {
        if (jt > 0) loadk(jt - 1);           // prefetch next (lower) tile
        const int buf = jt & 1;
        const bool diag = (jt == it);
        const int j0 = jt * TILE;
        #pragma unroll
        for (int st = 0; st < 4; st++) {
            f16x8 b0 = *(const f16x8*)&ks[buf][(st * 16 + m) * LDS_PITCH + 0  + quad * 8];
            f16x8 b1 = *(const f16x8*)&ks[buf][(st * 16 + m) * LDS_PITCH + 32 + quad * 8];
            f32x4 acc = {0.f, 0.f, 0.f, 0.f};
            acc = __builtin_amdgcn_mfma_f32_16x16x32_f16(a0, b0, acc, 0, 0, 0);
            acc = __builtin_amdgcn_mfma_f32_16x16x32_f16(a1, b1, acc, 0, 0, 0);
            const int j = j0 + st * 16 + m;
            const float rj = rbase[j];
            #pragma unroll
            for (int r = 0; r < 4; r++) {
                float val = __expf(acc[r] * rj) * il[r];
                if (diag && j > ib + r) val = il[r];   // exp(0)/l
                obase[(size_t)(ib + r) * SP1 + j] = val;
            }
        }
        if (jt > 0) writek((jt - 1) & 1);
        __syncthreads();
    }

    // ---------------- pass 2b: broadcast tiles, dwordx4 stores --------------
    // wave covers 4 rows x 64 cols per instruction (1024 B payload)
    for (int jt = it + 1; jt < NT; jt++) {
        const int j0 = jt * TILE;
        #pragma unroll
        for (int rb = 0; rb < 4; rb++) {
            int row = w * 16 + rb * 4 + (lane >> 4);
            float v = ils[row];
            f4u vv = {v, v, v, v};
            *(f4u*)&obase[(size_t)(i0 + row) * SP1 + j0 + (lane & 15) * 4] = vv;
        }
    }
}

// ---------------------------------------------------------------------------
extern "C" void kernel_launch(void* const* d_in, const int* in_sizes, int n_in,
                              void* d_out, int out_size, void* d_ws, size_t ws_size,
                              hipStream_t stream) {
    const float* q     = (const float*)d_in[0];
    const float* k     = (const float*)d_in[1];
    const float* sinks = (const float*)d_in[2];
    float* out = (float*)d_out;

    float* rinv = (float*)d_ws;   // BH*S floats

    knorm_kernel<<<dim3(BH * S / 4), 256, 0, stream>>>(k, rinv);
    fused_kernel<<<dim3(NT, BH), 256, 0, stream>>>(q, k, sinks, rinv, out);
}

// Round 4
// 683.455 us; speedup vs baseline: 1.1502x; 1.0207x over previous
//
#include <hip/hip_runtime.h>
#include <hip/hip_fp16.h>
#include <math.h>

// Problem constants
#define S 2048
#define D 64
#define BH 32          // B*H = 2*16
#define TILE 64
#define NT (S / TILE)  // 32
#define SP1 (S + 1)    // 2049
#define LOG2E 1.44269504088896f

typedef _Float16 f16;
typedef f16 f16x8 __attribute__((ext_vector_type(8)));
typedef f16 f16x4 __attribute__((ext_vector_type(4)));
typedef float f32x4 __attribute__((ext_vector_type(4)));

// 16-byte store with only 4-byte alignment guarantee (row stride 8196 B).
struct __attribute__((packed, aligned(4))) f4u { float x, y, z, w; };

#define LDS_PITCH 72   // halfs per row: 64 + 8 pad (2-way-max bank alias = free)

// ---------------------------------------------------------------------------
// prep_k: kh[j][d] = (f16)( k[j][d] / ||k_j|| * log2e )
// One wave per row; lane d holds k[j][d]. Normalization folded into K so the
// inner loop needs no rinv load/mul; log2e folded so exp(w) = v_exp_f32(acc).
// ---------------------------------------------------------------------------
__global__ __launch_bounds__(256) void prep_k(const float* __restrict__ k,
                                              f16* __restrict__ kh) {
    int row  = (blockIdx.x * 256 + threadIdx.x) >> 6;
    int lane = threadIdx.x & 63;
    float v = k[(size_t)row * D + lane];
    float s = v * v;
    #pragma unroll
    for (int off = 32; off; off >>= 1) s += __shfl_xor(s, off);
    kh[(size_t)row * D + lane] = (f16)(v * (1.0f / sqrtf(s)) * LOG2E);
}

// ---------------------------------------------------------------------------
// prep_q: straight f32 -> f16 convert, 8 elements/thread
// ---------------------------------------------------------------------------
__global__ __launch_bounds__(256) void prep_q(const float* __restrict__ q,
                                              f16* __restrict__ qh) {
    size_t t = (size_t)blockIdx.x * 256 + threadIdx.x;
    const float4* src = (const float4*)(q + t * 8);
    float4 v0 = src[0], v1 = src[1];
    f16x8 h;
    h[0] = (f16)v0.x; h[1] = (f16)v0.y; h[2] = (f16)v0.z; h[3] = (f16)v0.w;
    h[4] = (f16)v1.x; h[5] = (f16)v1.y; h[6] = (f16)v1.z; h[7] = (f16)v1.w;
    *(f16x8*)(qh + t * 8) = h;
}

// ---------------------------------------------------------------------------
// Fused: one block per (row-tile it, bh).
// MFMA with SWAPPED operands: A = K-hat tile (16 keys), B = Q (16 queries).
// D layout (col=lane&15, row=(lane>>4)*4+reg) then gives each lane
//   query  i = i0 + w*16 + (lane&15)          (fixed per lane)
//   keys   j = j0 + st*16 + (lane>>4)*4 + r   (4 CONSECUTIVE cols)
// -> pass-2a stores are one dwordx4 per lane per 16x16 subtile, and the
//    row-sum reduce is 2 shuffles (xor 16, 32).
// K tiles double-buffered with register-staged prefetch (one barrier/iter).
// ---------------------------------------------------------------------------
__global__ __launch_bounds__(256) void fused_kernel(
    const f16* __restrict__ qh, const f16* __restrict__ kh,
    const float* __restrict__ sinks, float* __restrict__ out)
{
    __shared__ __align__(16) f16 qs[TILE * LDS_PITCH];
    __shared__ __align__(16) f16 ks[2][TILE * LDS_PITCH];
    __shared__ float ils[TILE];

    const int it = NT - 1 - blockIdx.x;   // longest blocks first
    const int bh = blockIdx.y;
    const int i0 = it * TILE;
    const int tid  = threadIdx.x;
    const int lane = tid & 63;
    const int w    = tid >> 6;
    const int m    = lane & 15;
    const int quad = lane >> 4;
    const int srow = tid >> 2;            // staging: 4 threads per row
    const int sc   = (tid & 3) * 16;      // halfs; each thread covers 32 B

    const f16* qb = qh + (size_t)bh * S * D;
    const f16* kb = kh + (size_t)bh * S * D;
    float* obase = out + (size_t)bh * S * SP1;

    f16x8 pre0, pre1;   // in-flight K tile (register staged)

    auto loadk = [&](int jt) {
        const f16* tb = kb + (size_t)(jt * TILE + srow) * D + sc;
        pre0 = *(const f16x8*)tb;
        pre1 = *(const f16x8*)(tb + 8);
    };
    auto writek = [&](int buf) {
        *(f16x8*)&ks[buf][srow * LDS_PITCH + sc]     = pre0;
        *(f16x8*)&ks[buf][srow * LDS_PITCH + sc + 8] = pre1;
    };

    // prologue: K tile 0 + q tile staged together
    loadk(0);
    {
        const f16* tb = qb + (size_t)(i0 + srow) * D + sc;
        *(f16x8*)&qs[srow * LDS_PITCH + sc]     = *(const f16x8*)tb;
        *(f16x8*)&qs[srow * LDS_PITCH + sc + 8] = *(const f16x8*)(tb + 8);
    }
    writek(0);
    __syncthreads();

    // B fragments: queries w*16 + m, both K=32 halves of D=64
    f16x8 b0 = *(const f16x8*)&qs[(w * 16 + m) * LDS_PITCH + 0  + quad * 8];
    f16x8 b1 = *(const f16x8*)&qs[(w * 16 + m) * LDS_PITCH + 32 + quad * 8];

    const int iq = i0 + w * 16 + m;       // this lane's query row

    // ---------------- pass 1: row denominators ----------------
    float rowsum = 0.f;
    for (int jt = 0; jt <= it; jt++) {
        if (jt < it) loadk(jt + 1);
        const int buf = jt & 1;
        const bool diag = (jt == it);
        const int j0 = jt * TILE;
        #pragma unroll
        for (int st = 0; st < 4; st++) {
            f16x8 a0 = *(const f16x8*)&ks[buf][(st * 16 + m) * LDS_PITCH + 0  + quad * 8];
            f16x8 a1 = *(const f16x8*)&ks[buf][(st * 16 + m) * LDS_PITCH + 32 + quad * 8];
            f32x4 acc = {0.f, 0.f, 0.f, 0.f};
            acc = __builtin_amdgcn_mfma_f32_16x16x32_f16(a0, b0, acc, 0, 0, 0);
            acc = __builtin_amdgcn_mfma_f32_16x16x32_f16(a1, b1, acc, 0, 0, 0);
            const int jb = j0 + st * 16 + quad * 4;
            #pragma unroll
            for (int r = 0; r < 4; r++) {
                float e = exp2f(acc[r]);            // k-hat pre-scaled by log2e
                if (diag && (jb + r) > iq) e = 0.0f;
                rowsum += e;
            }
        }
        if (jt < it) writek((jt + 1) & 1);
        __syncthreads();
    }

    // reduce across the 4 quads (lanes m, m+16, m+32, m+48)
    rowsum += __shfl_xor(rowsum, 16);
    rowsum += __shfl_xor(rowsum, 32);

    if (lane < 16) {
        float l = rowsum + (float)(S - 1 - iq) + __expf(sinks[bh * S + iq]);
        ils[w * 16 + m] = 1.0f / l;
    }
    __syncthreads();

    // sink column (col S)
    if (tid < TILE) {
        int i = i0 + tid;
        obase[(size_t)i * SP1 + S] = __expf(sinks[bh * S + i]) * ils[tid];
    }

    const float il = ils[w * 16 + m];

    // ---------------- pass 2a: compute tiles, jt = it..0 (tile it resident) --
    for (int jt = it; jt >= 0; jt--) {
        if (jt > 0) loadk(jt - 1);
        const int buf = jt & 1;
        const bool diag = (jt == it);
        const int j0 = jt * TILE;
        #pragma unroll
        for (int st = 0; st < 4; st++) {
            f16x8 a0 = *(const f16x8*)&ks[buf][(st * 16 + m) * LDS_PITCH + 0  + quad * 8];
            f16x8 a1 = *(const f16x8*)&ks[buf][(st * 16 + m) * LDS_PITCH + 32 + quad * 8];
            f32x4 acc = {0.f, 0.f, 0.f, 0.f};
            acc = __builtin_amdgcn_mfma_f32_16x16x32_f16(a0, b0, acc, 0, 0, 0);
            acc = __builtin_amdgcn_mfma_f32_16x16x32_f16(a1, b1, acc, 0, 0, 0);
            const int jb = j0 + st * 16 + quad * 4;
            float v[4];
            #pragma unroll
            for (int r = 0; r < 4; r++) {
                v[r] = exp2f(acc[r]) * il;
                if (diag && (jb + r) > iq) v[r] = il;   // exp(0)/l
            }
            f4u vv = {v[0], v[1], v[2], v[3]};
            *(f4u*)&obase[(size_t)iq * SP1 + jb] = vv;
        }
        if (jt > 0) writek((jt - 1) & 1);
        __syncthreads();
    }

    // ---------------- pass 2b: broadcast tiles, dwordx4 stores --------------
    for (int jt = it + 1; jt < NT; jt++) {
        const int j0 = jt * TILE;
        #pragma unroll
        for (int rb = 0; rb < 4; rb++) {
            int row = w * 16 + rb * 4 + quad;
            float v = ils[row];
            f4u vv = {v, v, v, v};
            *(f4u*)&obase[(size_t)(i0 + row) * SP1 + j0 + m * 4] = vv;
        }
    }
}

// ---------------------------------------------------------------------------
extern "C" void kernel_launch(void* const* d_in, const int* in_sizes, int n_in,
                              void* d_out, int out_size, void* d_ws, size_t ws_size,
                              hipStream_t stream) {
    const float* q     = (const float*)d_in[0];
    const float* k     = (const float*)d_in[1];
    const float* sinks = (const float*)d_in[2];
    float* out = (float*)d_out;

    f16* kh = (f16*)d_ws;                         // BH*S*D halfs = 8 MB
    f16* qh = kh + (size_t)BH * S * D;            // 8 MB

    prep_k<<<dim3(BH * S / 4), 256, 0, stream>>>(k, kh);
    prep_q<<<dim3(BH * S * D / 8 / 256), 256, 0, stream>>>(q, qh);
    fused_kernel<<<dim3(NT, BH), 256, 0, stream>>>(qh, kh, sinks, out);
}